// Round 1
// baseline (1328.406 us; speedup 1.0000x reference)
//
#include <hip/hip_runtime.h>
#include <math.h>

#define ALPHA_SLOPE 0.2f

constexpr int B = 8, N = 2048, F = 256, D = 128, H = 2;
constexpr int TI = 16, TJ = 64;

__device__ __forceinline__ float lrelu(float x) { return fmaxf(x, ALPHA_SLOPE * x); }

// h{0,1}[row][col] = sum_k x[row][k] * W{h}[k][col] + b{h}[col]; 4 rows per block.
__global__ __launch_bounds__(256) void gemm_kernel(
    const float* __restrict__ x,
    const float* __restrict__ W0, const float* __restrict__ b0,
    const float* __restrict__ W1, const float* __restrict__ b1,
    float* __restrict__ h0, float* __restrict__ h1)
{
    __shared__ float xs[4][F];
    const int tid = threadIdx.x;
    const int row0 = blockIdx.x * 4;
    {
        const float4* xg = (const float4*)(x + (size_t)row0 * F);
        ((float4*)xs)[tid] = xg[tid];   // 4*256 floats = 256 float4
    }
    __syncthreads();
    const int head = tid >> 7, col = tid & (D - 1);
    const float* __restrict__ W = head ? W1 : W0;
    const float bv = (head ? b1 : b0)[col];
    float a0 = bv, a1 = bv, a2 = bv, a3 = bv;
#pragma unroll 8
    for (int k = 0; k < F; ++k) {
        const float w = W[k * D + col];
        a0 = fmaf(xs[0][k], w, a0);
        a1 = fmaf(xs[1][k], w, a1);
        a2 = fmaf(xs[2][k], w, a2);
        a3 = fmaf(xs[3][k], w, a3);
    }
    float* __restrict__ hh = head ? h1 : h0;
    hh[(size_t)(row0 + 0) * D + col] = a0;
    hh[(size_t)(row0 + 1) * D + col] = a1;
    hh[(size_t)(row0 + 2) * D + col] = a2;
    hh[(size_t)(row0 + 3) * D + col] = a3;
}

// l[row] = h[row]·a[0:D], r[row] = h[row]·a[D:2D]; one wave per (row,head).
__global__ __launch_bounds__(256) void lr_kernel(
    const float* __restrict__ h0, const float* __restrict__ h1,
    const float* __restrict__ a0, const float* __restrict__ a1,
    float* __restrict__ l0, float* __restrict__ r0,
    float* __restrict__ l1, float* __restrict__ r1)
{
    const int wave = threadIdx.x >> 6, lane = threadIdx.x & 63;
    const int rh = blockIdx.x * 4 + wave;   // [0, B*N*H)
    const int row = rh >> 1, head = rh & 1;
    const float* __restrict__ h = head ? h1 : h0;
    const float* __restrict__ a = head ? a1 : a0;
    const float hv0 = h[(size_t)row * D + lane];
    const float hv1 = h[(size_t)row * D + 64 + lane];
    float lv = hv0 * a[lane] + hv1 * a[64 + lane];
    float rv = hv0 * a[D + lane] + hv1 * a[D + 64 + lane];
#pragma unroll
    for (int off = 32; off; off >>= 1) {
        lv += __shfl_down(lv, off, 64);
        rv += __shfl_down(rv, off, 64);
    }
    if (lane == 0) {
        (head ? l1 : l0)[row] = lv;
        (head ? r1 : r0)[row] = rv;
    }
}

// top-2 of r per (b,head), with argmax index (for diagonal exclusion).
__global__ __launch_bounds__(256) void top2_kernel(
    const float* __restrict__ r0, const float* __restrict__ r1,
    float* __restrict__ rmax1, float* __restrict__ rmax2, int* __restrict__ ridx)
{
    const int bh = blockIdx.x;              // b = bh>>1, head = bh&1
    const float* __restrict__ r = ((bh & 1) ? r1 : r0) + (size_t)(bh >> 1) * N;
    const int tid = threadIdx.x;
    float m1 = -INFINITY, m2 = -INFINITY; int i1 = -1;
    for (int q = 0; q < N / 256; ++q) {
        const int j = q * 256 + tid;
        const float v = r[j];
        if (v > m1) { m2 = m1; m1 = v; i1 = j; }
        else if (v > m2) { m2 = v; }
    }
    __shared__ float sm1[256], sm2[256];
    __shared__ int si1[256];
    sm1[tid] = m1; sm2[tid] = m2; si1[tid] = i1;
    __syncthreads();
    if (tid == 0) {
        float M1 = sm1[0], M2 = sm2[0]; int I1 = si1[0];
        for (int t = 1; t < 256; ++t) {
            if (sm1[t] > M1) { M2 = fmaxf(M1, sm2[t]); M1 = sm1[t]; I1 = si1[t]; }
            else { M2 = fmaxf(M2, sm1[t]); }
        }
        rmax1[bh] = M1; rmax2[bh] = M2; ridx[bh] = I1;
    }
}

// Single-pass fused attention: out_i = elu(softmax_j(lrelu(l_i+r_j), j!=i) @ h + h_i)
// Block: 16 rows x 16 col-groups (8 cols each). h tile 64x128 staged in LDS.
__global__ __launch_bounds__(256) void attn_kernel(
    const float* __restrict__ h0, const float* __restrict__ h1,
    const float* __restrict__ l0v, const float* __restrict__ l1v,
    const float* __restrict__ r0v, const float* __restrict__ r1v,
    const float* __restrict__ rmax1, const float* __restrict__ rmax2,
    const int* __restrict__ ridx, float* __restrict__ out)
{
    const int head = blockIdx.y, b = blockIdx.z;
    const int bh = b * H + head;
    const float* __restrict__ h = (head ? h1 : h0) + (size_t)b * N * D;
    const float* __restrict__ lv = (head ? l1v : l0v) + (size_t)b * N;
    const float* __restrict__ rv = (head ? r1v : r0v) + (size_t)b * N;

    __shared__ float hs[TJ][D];
    __shared__ float rs[TJ];

    const int tid = threadIdx.x;
    const int ty = tid >> 4, tx = tid & 15;
    const int i = blockIdx.x * TI + ty;
    const float li = lv[i];
    const float rm = (i == ridx[bh]) ? rmax2[bh] : rmax1[bh];
    const float m = lrelu(li + rm);   // exact row max of masked scores

    float acc[8] = {0.f, 0.f, 0.f, 0.f, 0.f, 0.f, 0.f, 0.f};
    float Z = 0.f;

    for (int jt = 0; jt < N; jt += TJ) {
        const float4* hg = (const float4*)(h + (size_t)jt * D);
        float4* hs4 = (float4*)hs;
#pragma unroll
        for (int q = 0; q < (TJ * D) / (4 * 256); ++q)   // 8 float4 per thread
            hs4[q * 256 + tid] = hg[q * 256 + tid];
        if (tid < TJ) rs[tid] = rv[jt + tid];
        __syncthreads();
#pragma unroll 4
        for (int jj = 0; jj < TJ; ++jj) {
            const float t = li + rs[jj];
            const float s = fmaxf(t, ALPHA_SLOPE * t);
            float e = __expf(s - m);
            e = (jt + jj == i) ? 0.f : e;
            Z += e;
            const float4* hp = (const float4*)&hs[jj][tx * 8];
            const float4 v0 = hp[0], v1 = hp[1];
            acc[0] = fmaf(e, v0.x, acc[0]);
            acc[1] = fmaf(e, v0.y, acc[1]);
            acc[2] = fmaf(e, v0.z, acc[2]);
            acc[3] = fmaf(e, v0.w, acc[3]);
            acc[4] = fmaf(e, v1.x, acc[4]);
            acc[5] = fmaf(e, v1.y, acc[5]);
            acc[6] = fmaf(e, v1.z, acc[6]);
            acc[7] = fmaf(e, v1.w, acc[7]);
        }
        __syncthreads();
    }

    const float inv = 1.f / Z;
    const float4* hi = (const float4*)(h + (size_t)i * D + tx * 8);
    const float4 g0 = hi[0], g1 = hi[1];
    float o[8];
    o[0] = fmaf(acc[0], inv, g0.x);
    o[1] = fmaf(acc[1], inv, g0.y);
    o[2] = fmaf(acc[2], inv, g0.z);
    o[3] = fmaf(acc[3], inv, g0.w);
    o[4] = fmaf(acc[4], inv, g1.x);
    o[5] = fmaf(acc[5], inv, g1.y);
    o[6] = fmaf(acc[6], inv, g1.z);
    o[7] = fmaf(acc[7], inv, g1.w);
#pragma unroll
    for (int q = 0; q < 8; ++q)
        o[q] = o[q] > 0.f ? o[q] : (__expf(o[q]) - 1.f);   // elu, alpha=1

    float* op = out + (size_t)(b * N + i) * (H * D) + head * D + tx * 8;
    ((float4*)op)[0] = make_float4(o[0], o[1], o[2], o[3]);
    ((float4*)op)[1] = make_float4(o[4], o[5], o[6], o[7]);
}

extern "C" void kernel_launch(void* const* d_in, const int* in_sizes, int n_in,
                              void* d_out, int out_size, void* d_ws, size_t ws_size,
                              hipStream_t stream)
{
    const float* x = (const float*)d_in[0];
    float* ws = (float*)d_ws;
    size_t off = 0;
    float* xbuf = ws + off; off += (size_t)B * N * F;   // layer-0 output (concat heads)
    float* h0   = ws + off; off += (size_t)B * N * D;
    float* h1   = ws + off; off += (size_t)B * N * D;
    float* l0   = ws + off; off += (size_t)B * N;
    float* r0   = ws + off; off += (size_t)B * N;
    float* l1   = ws + off; off += (size_t)B * N;
    float* r1   = ws + off; off += (size_t)B * N;
    float* rm1  = ws + off; off += 16;
    float* rm2  = ws + off; off += 16;
    int*   rix  = (int*)(ws + off); off += 16;

    for (int layer = 0; layer < 2; ++layer) {
        const float* xin = layer ? xbuf : x;
        float* xout = layer ? (float*)d_out : xbuf;
        const int base = 2 + layer * 6;
        const float* W0 = (const float*)d_in[base + 0];
        const float* b0 = (const float*)d_in[base + 1];
        const float* a0 = (const float*)d_in[base + 2];
        const float* W1 = (const float*)d_in[base + 3];
        const float* b1 = (const float*)d_in[base + 4];
        const float* a1 = (const float*)d_in[base + 5];

        gemm_kernel<<<B * N / 4, 256, 0, stream>>>(xin, W0, b0, W1, b1, h0, h1);
        lr_kernel<<<B * N * H / 4, 256, 0, stream>>>(h0, h1, a0, a1, l0, r0, l1, r1);
        top2_kernel<<<B * H, 256, 0, stream>>>(r0, r1, rm1, rm2, rix);
        attn_kernel<<<dim3(N / TI, H, B), 256, 0, stream>>>(h0, h1, l0, l1, r0, r1,
                                                            rm1, rm2, rix, xout);
    }
}

// Round 2
// 398.744 us; speedup vs baseline: 3.3315x; 3.3315x over previous
//
#include <hip/hip_runtime.h>
#include <math.h>

#define ALPHA_SLOPE 0.2f

typedef _Float16 f16;
typedef f16 f16x8 __attribute__((ext_vector_type(8)));
typedef float f32x4 __attribute__((ext_vector_type(4)));

constexpr int B_ = 8, N = 2048, F = 256, D = 128, H = 2;
constexpr int TI = 64;        // rows per attention block
constexpr int TJ = 128;       // K-tile (j) per iteration
constexpr int PJ = TJ + 8;    // padded LDS row in f16 units (272 B, 16B-aligned)

__device__ __forceinline__ float lrelu(float x) { return fmaxf(x, ALPHA_SLOPE * x); }

// ---------------- h = x@W + b (both heads), 4 rows/block ----------------
__global__ __launch_bounds__(256) void gemm_kernel(
    const float* __restrict__ x,
    const float* __restrict__ W0, const float* __restrict__ b0,
    const float* __restrict__ W1, const float* __restrict__ b1,
    float* __restrict__ h0, float* __restrict__ h1)
{
    __shared__ float xs[4][F];
    const int tid = threadIdx.x;
    const int row0 = blockIdx.x * 4;
    {
        const float4* xg = (const float4*)(x + (size_t)row0 * F);
        ((float4*)xs)[tid] = xg[tid];
    }
    __syncthreads();
    const int head = tid >> 7, col = tid & (D - 1);
    const float* __restrict__ W = head ? W1 : W0;
    const float bv = (head ? b1 : b0)[col];
    float a0 = bv, a1 = bv, a2 = bv, a3 = bv;
#pragma unroll 8
    for (int k = 0; k < F; ++k) {
        const float w = W[k * D + col];
        a0 = fmaf(xs[0][k], w, a0);
        a1 = fmaf(xs[1][k], w, a1);
        a2 = fmaf(xs[2][k], w, a2);
        a3 = fmaf(xs[3][k], w, a3);
    }
    float* __restrict__ hh = head ? h1 : h0;
    hh[(size_t)(row0 + 0) * D + col] = a0;
    hh[(size_t)(row0 + 1) * D + col] = a1;
    hh[(size_t)(row0 + 2) * D + col] = a2;
    hh[(size_t)(row0 + 3) * D + col] = a3;
}

// ---------------- l,r per (row,head): one wave each ----------------
__global__ __launch_bounds__(256) void lr_kernel(
    const float* __restrict__ h0, const float* __restrict__ h1,
    const float* __restrict__ a0, const float* __restrict__ a1,
    float* __restrict__ l0, float* __restrict__ r0,
    float* __restrict__ l1, float* __restrict__ r1)
{
    const int wave = threadIdx.x >> 6, lane = threadIdx.x & 63;
    const int rh = blockIdx.x * 4 + wave;
    const int row = rh >> 1, head = rh & 1;
    const float* __restrict__ h = head ? h1 : h0;
    const float* __restrict__ a = head ? a1 : a0;
    const float hv0 = h[(size_t)row * D + lane];
    const float hv1 = h[(size_t)row * D + 64 + lane];
    float lv = hv0 * a[lane] + hv1 * a[64 + lane];
    float rv = hv0 * a[D + lane] + hv1 * a[D + 64 + lane];
#pragma unroll
    for (int off = 32; off; off >>= 1) {
        lv += __shfl_down(lv, off, 64);
        rv += __shfl_down(rv, off, 64);
    }
    if (lane == 0) {
        (head ? l1 : l0)[row] = lv;
        (head ? r1 : r0)[row] = rv;
    }
}

// ---------------- top-2 of r per (b,head), with argmax ----------------
__global__ __launch_bounds__(256) void top2_kernel(
    const float* __restrict__ r0, const float* __restrict__ r1,
    float* __restrict__ rmax1, float* __restrict__ rmax2, int* __restrict__ ridx)
{
    const int bh = blockIdx.x;
    const float* __restrict__ r = ((bh & 1) ? r1 : r0) + (size_t)(bh >> 1) * N;
    const int tid = threadIdx.x;
    float m1 = -INFINITY, m2 = -INFINITY; int i1 = -1;
    for (int q = 0; q < N / 256; ++q) {
        const int j = q * 256 + tid;
        const float v = r[j];
        if (v > m1) { m2 = m1; m1 = v; i1 = j; }
        else if (v > m2) { m2 = v; }
    }
    __shared__ float sm1[256], sm2[256];
    __shared__ int si1[256];
    sm1[tid] = m1; sm2[tid] = m2; si1[tid] = i1;
    __syncthreads();
    if (tid == 0) {
        float M1 = sm1[0], M2 = sm2[0]; int I1 = si1[0];
        for (int t = 1; t < 256; ++t) {
            if (sm1[t] > M1) { M2 = fmaxf(M1, sm2[t]); M1 = sm1[t]; I1 = si1[t]; }
            else { M2 = fmaxf(M2, sm1[t]); }
        }
        rmax1[bh] = M1; rmax2[bh] = M2; ridx[bh] = I1;
    }
}

// ---------------- h [b][j][d] fp32 -> hT [b][h][d][j] f16 ----------------
__global__ __launch_bounds__(256) void transpose_kernel(
    const float* __restrict__ h0, const float* __restrict__ h1, f16* __restrict__ hT)
{
    const int b = blockIdx.z;
    const int head = blockIdx.y >> 1;
    const int d0 = (blockIdx.y & 1) * 64;
    const int j0 = blockIdx.x * 64;
    const float* __restrict__ h = (head ? h1 : h0) + (size_t)b * N * D;
    __shared__ float ts[64][65];
    const int t = threadIdx.x;
#pragma unroll
    for (int p = 0; p < 4; ++p) {
        const int j = p * 16 + (t >> 4);
        const float4 v = *(const float4*)&h[(size_t)(j0 + j) * D + d0 + (t & 15) * 4];
        ts[j][(t & 15) * 4 + 0] = v.x;
        ts[j][(t & 15) * 4 + 1] = v.y;
        ts[j][(t & 15) * 4 + 2] = v.z;
        ts[j][(t & 15) * 4 + 3] = v.w;
    }
    __syncthreads();
    const int d = t >> 2, jc = (t & 3) * 16;
    f16x8 v0, v1;
#pragma unroll
    for (int q = 0; q < 8; ++q) {
        v0[q] = (f16)ts[jc + q][d];
        v1[q] = (f16)ts[jc + 8 + q][d];
    }
    f16* dst = hT + ((size_t)(b * H + head) * D + d0 + d) * N + j0 + jc;
    *(f16x8*)dst = v0;
    *(f16x8*)(dst + 8) = v1;
}

// ---------------- fused MFMA attention ----------------
// Block: 64 rows x 128 cols (full D), 4 waves; K-tiled over j in chunks of 128.
// P[i][j] = exp(lrelu(l_i+r_j) - m_i) built in LDS (f16), h^T staged in LDS (f16),
// C = P@h via mfma_f32_16x16x32_f16; epilogue: *1/Z + h_i, elu.
__global__ __launch_bounds__(256) void attn_mfma_kernel(
    const float* __restrict__ h0, const float* __restrict__ h1,
    const f16* __restrict__ hT,
    const float* __restrict__ l0v, const float* __restrict__ l1v,
    const float* __restrict__ r0v, const float* __restrict__ r1v,
    const float* __restrict__ rmax1, const float* __restrict__ rmax2,
    const int* __restrict__ ridx, float* __restrict__ out)
{
    const int head = blockIdx.y, b = blockIdx.z;
    const int bh = b * H + head;
    const int i0 = blockIdx.x * TI;
    const float* __restrict__ hin = (head ? h1 : h0) + (size_t)b * N * D;
    const f16* __restrict__ hTb = hT + (size_t)bh * D * N;
    const float* __restrict__ lv = (head ? l1v : l0v) + (size_t)b * N;
    const float* __restrict__ rv = (head ? r1v : r0v) + (size_t)b * N;

    __shared__ f16 Pl[TI][PJ];     // 17408 B
    __shared__ f16 Hs[D][PJ];      // 34816 B
    __shared__ float Zl[TI][4];
    __shared__ float Zinv[TI];

    const int t = threadIdx.x;
    const int w = t >> 6, l = t & 63;

    // P-producer role: row pm, j-group pjg (32 j's each)
    const int pm = t & 63, pjg = t >> 6;
    const int irow = i0 + pm;
    const float li = lv[irow];
    const float rmx = (irow == ridx[bh]) ? rmax2[bh] : rmax1[bh];
    const float mrow = lrelu(li + rmx);   // exact max of masked scores in this row
    float Zpart = 0.f;

    // fragment role
    const int fm = l & 15, fk = (l >> 4) * 8;

    f32x4 acc[4][2] = {};

    for (int jt = 0; jt < N; jt += TJ) {
        __syncthreads();   // previous iteration's fragment reads complete
        // ---- stage hT tile: Hs[d][0..127] = hT[d][jt..jt+127], 2048 16B chunks ----
#pragma unroll
        for (int p = 0; p < 8; ++p) {
            const int q = p * 256 + t;
            const int d = q >> 4, c = q & 15;
            *(f16x8*)&Hs[d][c * 8] = *(const f16x8*)&hTb[(size_t)d * N + jt + c * 8];
        }
        // ---- build P tile: row pm, j = jt + pjg*32 + [0,32) ----
#pragma unroll
        for (int c = 0; c < 4; ++c) {
            const int jb = jt + pjg * 32 + c * 8;
            const float4 ra = *(const float4*)&rv[jb];
            const float4 rb = *(const float4*)&rv[jb + 4];
            float e[8];
            e[0] = ra.x; e[1] = ra.y; e[2] = ra.z; e[3] = ra.w;
            e[4] = rb.x; e[5] = rb.y; e[6] = rb.z; e[7] = rb.w;
            f16x8 pv;
#pragma unroll
            for (int q = 0; q < 8; ++q) {
                const float s = lrelu(li + e[q]);
                float ev = __expf(s - mrow);
                ev = (jb + q == irow) ? 0.f : ev;
                Zpart += ev;
                pv[q] = (f16)ev;
            }
            *(f16x8*)&Pl[pm][pjg * 32 + c * 8] = pv;
        }
        __syncthreads();   // P + Hs ready
        // ---- MFMA: 4 K-steps of 32 ----
#pragma unroll
        for (int ks = 0; ks < 4; ++ks) {
            f16x8 af[4], bf[2];
#pragma unroll
            for (int rt = 0; rt < 4; ++rt)
                af[rt] = *(const f16x8*)&Pl[rt * 16 + fm][ks * 32 + fk];
#pragma unroll
            for (int ct = 0; ct < 2; ++ct)
                bf[ct] = *(const f16x8*)&Hs[w * 32 + ct * 16 + fm][ks * 32 + fk];
#pragma unroll
            for (int rt = 0; rt < 4; ++rt)
#pragma unroll
                for (int ct = 0; ct < 2; ++ct)
                    acc[rt][ct] = __builtin_amdgcn_mfma_f32_16x16x32_f16(
                        af[rt], bf[ct], acc[rt][ct], 0, 0, 0);
        }
    }

    // ---- Z reduction ----
    Zl[pm][pjg] = Zpart;
    __syncthreads();
    if (t < TI) {
        const float z = Zl[t][0] + Zl[t][1] + Zl[t][2] + Zl[t][3];
        Zinv[t] = 1.f / z;
    }
    __syncthreads();

    // ---- epilogue: /Z, +h_i, elu, store ----
#pragma unroll
    for (int rt = 0; rt < 4; ++rt) {
#pragma unroll
        for (int ct = 0; ct < 2; ++ct) {
            const int col = w * 32 + ct * 16 + fm;
#pragma unroll
            for (int q = 0; q < 4; ++q) {
                const int row = rt * 16 + (l >> 4) * 4 + q;
                float v = acc[rt][ct][q] * Zinv[row]
                        + hin[(size_t)(i0 + row) * D + col];
                v = v > 0.f ? v : (__expf(v) - 1.f);
                out[((size_t)(b * N + i0 + row)) * (H * D) + head * D + col] = v;
            }
        }
    }
}

extern "C" void kernel_launch(void* const* d_in, const int* in_sizes, int n_in,
                              void* d_out, int out_size, void* d_ws, size_t ws_size,
                              hipStream_t stream)
{
    const float* x = (const float*)d_in[0];
    float* ws = (float*)d_ws;
    size_t off = 0;
    float* xbuf = ws + off; off += (size_t)B_ * N * F;        // layer-0 output
    float* h0   = ws + off; off += (size_t)B_ * N * D;
    float* h1   = ws + off; off += (size_t)B_ * N * D;
    f16*   hT   = (f16*)(ws + off); off += (size_t)B_ * H * D * N / 2;  // f16
    float* l0   = ws + off; off += (size_t)B_ * N;
    float* r0   = ws + off; off += (size_t)B_ * N;
    float* l1   = ws + off; off += (size_t)B_ * N;
    float* r1   = ws + off; off += (size_t)B_ * N;
    float* rm1  = ws + off; off += 16;
    float* rm2  = ws + off; off += 16;
    int*   rix  = (int*)(ws + off); off += 16;

    for (int layer = 0; layer < 2; ++layer) {
        const float* xin = layer ? xbuf : x;
        float* xout = layer ? (float*)d_out : xbuf;
        const int base = 2 + layer * 6;
        const float* W0 = (const float*)d_in[base + 0];
        const float* b0 = (const float*)d_in[base + 1];
        const float* a0 = (const float*)d_in[base + 2];
        const float* W1 = (const float*)d_in[base + 3];
        const float* b1 = (const float*)d_in[base + 4];
        const float* a1 = (const float*)d_in[base + 5];

        gemm_kernel<<<B_ * N / 4, 256, 0, stream>>>(xin, W0, b0, W1, b1, h0, h1);
        lr_kernel<<<B_ * N * H / 4, 256, 0, stream>>>(h0, h1, a0, a1, l0, r0, l1, r1);
        top2_kernel<<<B_ * H, 256, 0, stream>>>(r0, r1, rm1, rm2, rix);
        transpose_kernel<<<dim3(N / 64, H * 2, B_), 256, 0, stream>>>(h0, h1, hT);
        attn_mfma_kernel<<<dim3(N / TI, H, B_), 256, 0, stream>>>(
            h0, h1, hT, l0, l1, r0, r1, rm1, rm2, rix, xout);
    }
}

// Round 3
// 387.079 us; speedup vs baseline: 3.4319x; 1.0301x over previous
//
#include <hip/hip_runtime.h>
#include <math.h>

#define ALPHA_SLOPE 0.2f

typedef _Float16 f16;
typedef f16 f16x4 __attribute__((ext_vector_type(4)));
typedef f16 f16x8 __attribute__((ext_vector_type(8)));
typedef float f32x4 __attribute__((ext_vector_type(4)));

constexpr int B_ = 8, N = 2048, F = 256, D = 128, H = 2;
constexpr int C2 = H * D;           // 256 = feature width = K of gemm
constexpr int M_ = B_ * N;          // 16384 rows
constexpr int NCH = 16;             // scan chunks
constexpr int CHL = N / NCH;        // 128 j per chunk

__device__ __forceinline__ float lrelu(float x) { return fmaxf(x, ALPHA_SLOPE * x); }

// ---------- x fp32 -> f16 ----------
__global__ __launch_bounds__(256) void cvt_x_kernel(const float* __restrict__ x, f16* __restrict__ xh)
{
    const int idx = (blockIdx.x * 256 + threadIdx.x) * 4;
    const float4 v = *(const float4*)&x[idx];
    f16x4 o; o[0] = (f16)v.x; o[1] = (f16)v.y; o[2] = (f16)v.z; o[3] = (f16)v.w;
    *(f16x4*)&xh[idx] = o;
}

// ---------- WcT[c][k] = W(head(c))[k][c%128], f16 ----------
__global__ __launch_bounds__(256) void cvt_w_kernel(const float* __restrict__ W0,
                                                    const float* __restrict__ W1,
                                                    f16* __restrict__ WcT)
{
    const int c = blockIdx.x, k = threadIdx.x;
    const float v = (c < D) ? W0[k * D + c] : W1[k * D + (c - D)];
    WcT[c * C2 + k] = (f16)v;
}

// ---------- h[M][256] = xh @ WcT^T + bias, MFMA ----------
__global__ __launch_bounds__(256) void gemm_mfma_kernel(
    const f16* __restrict__ xh, const f16* __restrict__ WcT,
    const float* __restrict__ b0, const float* __restrict__ b1,
    float* __restrict__ h)
{
    __shared__ f16 xs[64][C2 + 8];
    const int t = threadIdx.x;
    const int row0 = blockIdx.x * 64;
#pragma unroll
    for (int p = 0; p < 8; ++p) {
        const int q = p * 256 + t;
        const int row = q >> 5, cc = q & 31;
        *(f16x8*)&xs[row][cc * 8] = *(const f16x8*)&xh[(size_t)(row0 + row) * C2 + cc * 8];
    }
    __syncthreads();
    const int w = t >> 6, l = t & 63;
    const int fm = l & 15, fk = (l >> 4) * 8;
    f32x4 acc[4][4] = {};
#pragma unroll
    for (int ks = 0; ks < 8; ++ks) {
        f16x8 af[4], bf[4];
#pragma unroll
        for (int rt = 0; rt < 4; ++rt)
            af[rt] = *(const f16x8*)&xs[rt * 16 + fm][ks * 32 + fk];
#pragma unroll
        for (int ct = 0; ct < 4; ++ct) {
            const int col = w * 64 + ct * 16 + fm;
            bf[ct] = *(const f16x8*)&WcT[(size_t)col * C2 + ks * 32 + fk];
        }
#pragma unroll
        for (int rt = 0; rt < 4; ++rt)
#pragma unroll
            for (int ct = 0; ct < 4; ++ct)
                acc[rt][ct] = __builtin_amdgcn_mfma_f32_16x16x32_f16(af[rt], bf[ct], acc[rt][ct], 0, 0, 0);
    }
#pragma unroll
    for (int rt = 0; rt < 4; ++rt)
#pragma unroll
        for (int ct = 0; ct < 4; ++ct) {
            const int col = w * 64 + ct * 16 + fm;
            const float bias = (col < D) ? b0[col] : b1[col - D];
#pragma unroll
            for (int q = 0; q < 4; ++q) {
                const int row = rt * 16 + (l >> 4) * 4 + q;
                h[(size_t)(row0 + row) * C2 + col] = acc[rt][ct][q] + bias;
            }
        }
}

// ---------- l,r per (row,head) ----------
__global__ __launch_bounds__(256) void lr_kernel(
    const float* __restrict__ h,
    const float* __restrict__ a0, const float* __restrict__ a1,
    float* __restrict__ l0, float* __restrict__ r0,
    float* __restrict__ l1, float* __restrict__ r1)
{
    const int wave = threadIdx.x >> 6, lane = threadIdx.x & 63;
    const int rh = blockIdx.x * 4 + wave;
    const int row = rh >> 1, head = rh & 1;
    const float* __restrict__ hr = h + (size_t)row * C2 + head * D;
    const float* __restrict__ a = head ? a1 : a0;
    const float hv0 = hr[lane];
    const float hv1 = hr[64 + lane];
    float lv = hv0 * a[lane] + hv1 * a[64 + lane];
    float rv = hv0 * a[D + lane] + hv1 * a[D + 64 + lane];
#pragma unroll
    for (int off = 32; off; off >>= 1) {
        lv += __shfl_down(lv, off, 64);
        rv += __shfl_down(rv, off, 64);
    }
    if (lane == 0) {
        (head ? l1 : l0)[row] = lv;
        (head ? r1 : r0)[row] = rv;
    }
}

// ---------- top-2 of r per (b,head) ----------
__global__ __launch_bounds__(256) void top2_kernel(
    const float* __restrict__ r0, const float* __restrict__ r1,
    float* __restrict__ rmax1, float* __restrict__ rmax2, int* __restrict__ ridx)
{
    const int bh = blockIdx.x;
    const float* __restrict__ r = ((bh & 1) ? r1 : r0) + (size_t)(bh >> 1) * N;
    const int tid = threadIdx.x;
    float m1 = -INFINITY, m2 = -INFINITY; int i1 = -1;
    for (int q = 0; q < N / 256; ++q) {
        const int j = q * 256 + tid;
        const float v = r[j];
        if (v > m1) { m2 = m1; m1 = v; i1 = j; }
        else if (v > m2) { m2 = v; }
    }
    __shared__ float sm1[256], sm2[256];
    __shared__ int si1[256];
    sm1[tid] = m1; sm2[tid] = m2; si1[tid] = i1;
    __syncthreads();
    if (tid == 0) {
        float M1 = sm1[0], M2 = sm2[0]; int I1 = si1[0];
        for (int t = 1; t < 256; ++t) {
            if (sm1[t] > M1) { M2 = fmaxf(M1, sm2[t]); M1 = sm1[t]; I1 = si1[t]; }
            else { M2 = fmaxf(M2, sm1[t]); }
        }
        rmax1[bh] = M1; rmax2[bh] = M2; ridx[bh] = I1;
    }
}

// ---------- sort r desc (bitonic, per bh) + weights + scalar prefix/suffix sums ----------
__global__ __launch_bounds__(256) void sort_kernel(
    const float* __restrict__ r0, const float* __restrict__ r1,
    float* __restrict__ rs_s, int* __restrict__ perm,
    float* __restrict__ As, float* __restrict__ Bs,
    float* __restrict__ SAinc, float* __restrict__ SSBinc)
{
    const int bh = blockIdx.x;
    const float* __restrict__ r = ((bh & 1) ? r1 : r0) + (size_t)(bh >> 1) * N;
    __shared__ float key[N];
    __shared__ int val[N];
    __shared__ float ss[256], ss2[256];
    const int t = threadIdx.x;
    for (int j = t; j < N; j += 256) { key[j] = r[j]; val[j] = j; }
    __syncthreads();
    for (int k = 2; k <= N; k <<= 1) {
        for (int j = k >> 1; j > 0; j >>= 1) {
#pragma unroll 2
            for (int base = 0; base < N; base += 256) {
                const int i = base + t;
                const int ixj = i ^ j;
                if (ixj > i) {
                    const bool desc = ((i & k) == 0);
                    const float a = key[i], b = key[ixj];
                    if (desc ? (a < b) : (a > b)) {
                        key[i] = b; key[ixj] = a;
                        const int va = val[i]; val[i] = val[ixj]; val[ixj] = va;
                    }
                }
            }
            __syncthreads();
        }
    }
    const float c1 = key[0];
    const int base = t * 8;
    float eA[8], eB[8];
    float sA = 0.f, sB = 0.f;
#pragma unroll
    for (int q = 0; q < 8; ++q) {
        const float rr = key[base + q];
        eA[q] = __expf(rr - c1);
        eB[q] = __expf(0.2f * (rr - c1));
        sA += eA[q]; sB += eB[q];
    }
    ss[t] = sA; ss2[255 - t] = sB;
    __syncthreads();
    for (int off = 1; off < 256; off <<= 1) {
        const float v1 = (t >= off) ? ss[t - off] : 0.f;
        const float v2 = (t >= off) ? ss2[t - off] : 0.f;
        __syncthreads();
        ss[t] += v1; ss2[t] += v2;
        __syncthreads();
    }
    const float exclA = ss[t] - sA;
    const float exclB = ss2[255 - t] - sB;
    const size_t g = (size_t)bh * N;
    float accA = exclA;
#pragma unroll
    for (int q = 0; q < 8; ++q) {
        accA += eA[q];
        SAinc[g + base + q] = accA;
        As[g + base + q] = eA[q];
        Bs[g + base + q] = eB[q];
        rs_s[g + base + q] = key[base + q];
        perm[g + base + q] = val[base + q];
    }
    float accB = exclB;
#pragma unroll
    for (int q = 7; q >= 0; --q) {
        accB += eB[q];
        SSBinc[g + base + q] = accB;
    }
}

// ---------- per-chunk vector scans: PA (prefix of A*h), PB (suffix of B*h), chunk totals ----------
__global__ __launch_bounds__(256) void scanA_kernel(
    const float* __restrict__ h, const int* __restrict__ perm,
    const float* __restrict__ As, const float* __restrict__ Bs,
    f16* __restrict__ PA, f16* __restrict__ PB,
    float* __restrict__ totA, float* __restrict__ totB)
{
    const int chunk = blockIdx.x, bh = blockIdx.y;
    const int b = bh >> 1, head = bh & 1;
    __shared__ float hs[CHL][D];
    __shared__ int pj[CHL];
    __shared__ float wA[CHL], wB[CHL];
    const int t = threadIdx.x;
    const size_t g = (size_t)bh * N + chunk * CHL;
    if (t < CHL) {
        pj[t] = perm[g + t];
        wA[t] = As[g + t];
        wB[t] = Bs[g + t];
    }
    __syncthreads();
#pragma unroll
    for (int p = 0; p < 16; ++p) {
        const int q = p * 256 + t;
        const int row = q >> 5, c4 = q & 31;
        const float* src = h + (size_t)(b * N + pj[row]) * C2 + head * D;
        *(float4*)&hs[row][c4 * 4] = *(const float4*)&src[c4 * 4];
    }
    __syncthreads();
    if (t < D) {
        const int d = t;
        float acc = 0.f;
        for (int j = 0; j < CHL; ++j) {
            acc = fmaf(wA[j], hs[j][d], acc);
            PA[(g + j) * D + d] = (f16)acc;
        }
        totA[(size_t)(bh * NCH + chunk) * D + d] = acc;
    } else {
        const int d = t - D;
        float acc = 0.f;
        for (int jj = 0; jj < CHL; ++jj) {
            const int j = CHL - 1 - jj;
            acc = fmaf(wB[j], hs[j][d], acc);
            PB[(g + j) * D + d] = (f16)acc;
        }
        totB[(size_t)(bh * NCH + chunk) * D + d] = acc;
    }
}

// ---------- chunk-offset scans ----------
__global__ __launch_bounds__(128) void scanB_kernel(
    const float* __restrict__ totA, const float* __restrict__ totB,
    float* __restrict__ AOff, float* __restrict__ BOffS)
{
    const int bh = blockIdx.x, d = threadIdx.x;
    float accA = 0.f;
    for (int q = 0; q < NCH; ++q) {
        AOff[(size_t)(bh * NCH + q) * D + d] = accA;
        accA += totA[(size_t)(bh * NCH + q) * D + d];
    }
    float accB = 0.f;
    for (int q = NCH - 1; q >= 0; --q) {
        BOffS[(size_t)(bh * NCH + q) * D + d] = accB;
        accB += totB[(size_t)(bh * NCH + q) * D + d];
    }
}

// ---------- output: per row lookup + combine + elu ----------
__global__ __launch_bounds__(256) void out_kernel(
    const float* __restrict__ h,
    const float* __restrict__ l0v, const float* __restrict__ l1v,
    const float* __restrict__ r0v, const float* __restrict__ r1v,
    const float* __restrict__ rmax1, const float* __restrict__ rmax2,
    const int* __restrict__ ridx, const float* __restrict__ rs_s,
    const float* __restrict__ SAinc, const float* __restrict__ SSBinc,
    const f16* __restrict__ PA, const f16* __restrict__ PB,
    const float* __restrict__ AOff, const float* __restrict__ BOffS,
    float* __restrict__ out_f32, f16* __restrict__ out_f16, const int final_layer)
{
    const int head = blockIdx.y, b = blockIdx.z;
    const int bh = b * H + head;
    const float* __restrict__ lv = (head ? l1v : l0v) + (size_t)b * N;
    const float* __restrict__ rv = (head ? r1v : r0v) + (size_t)b * N;
    __shared__ float rsl[N];
    const int t = threadIdx.x;
    for (int j = t; j < N; j += 256) rsl[j] = rs_s[(size_t)bh * N + j];
    __syncthreads();

    const int i = blockIdx.x * 16 + (t >> 4);
    const int c0 = (t & 15) * 8;
    const float li = lv[i];
    const float ri = rv[i];
    const float rmx = (i == ridx[bh]) ? rmax2[bh] : rmax1[bh];
    const float m = lrelu(li + rmx);
    const float c1 = rmax1[bh];
    const float alpha = __expf(li + c1 - m);
    const float beta = __expf(0.2f * (li + c1) - m);
    const float diag = __expf(lrelu(li + ri) - m);

    int lo = 0, hi = N;
    const float thr = -li;
    while (lo < hi) {
        const int mid = (lo + hi) >> 1;
        if (rsl[mid] >= thr) lo = mid + 1; else hi = mid;
    }
    const int k = lo;

    const float SAk = (k > 0) ? SAinc[(size_t)bh * N + k - 1] : 0.f;
    const float SBk = (k < N) ? SSBinc[(size_t)bh * N + k] : 0.f;
    const float Z = fmaf(alpha, SAk, beta * SBk) - diag;
    const float invZ = 1.f / Z;

    float pa[8] = {}, pb[8] = {};
    if (k > 0) {
        const int kk = k - 1, ch = kk >> 7;
        const f16x8 v = *(const f16x8*)&PA[((size_t)bh * N + kk) * D + c0];
        const float4 o0 = *(const float4*)&AOff[(size_t)(bh * NCH + ch) * D + c0];
        const float4 o1 = *(const float4*)&AOff[(size_t)(bh * NCH + ch) * D + c0 + 4];
        pa[0] = (float)v[0] + o0.x; pa[1] = (float)v[1] + o0.y;
        pa[2] = (float)v[2] + o0.z; pa[3] = (float)v[3] + o0.w;
        pa[4] = (float)v[4] + o1.x; pa[5] = (float)v[5] + o1.y;
        pa[6] = (float)v[6] + o1.z; pa[7] = (float)v[7] + o1.w;
    }
    if (k < N) {
        const int ch = k >> 7;
        const f16x8 v = *(const f16x8*)&PB[((size_t)bh * N + k) * D + c0];
        const float4 o0 = *(const float4*)&BOffS[(size_t)(bh * NCH + ch) * D + c0];
        const float4 o1 = *(const float4*)&BOffS[(size_t)(bh * NCH + ch) * D + c0 + 4];
        pb[0] = (float)v[0] + o0.x; pb[1] = (float)v[1] + o0.y;
        pb[2] = (float)v[2] + o0.z; pb[3] = (float)v[3] + o0.w;
        pb[4] = (float)v[4] + o1.x; pb[5] = (float)v[5] + o1.y;
        pb[6] = (float)v[6] + o1.z; pb[7] = (float)v[7] + o1.w;
    }

    const float* hr = h + (size_t)(b * N + i) * C2 + head * D + c0;
    const float4 h0v = *(const float4*)&hr[0];
    const float4 h1v = *(const float4*)&hr[4];
    const float hv[8] = {h0v.x, h0v.y, h0v.z, h0v.w, h1v.x, h1v.y, h1v.z, h1v.w};
    float o[8];
#pragma unroll
    for (int q = 0; q < 8; ++q) {
        const float num = alpha * pa[q] + beta * pb[q] - diag * hv[q];
        float v = fmaf(num, invZ, hv[q]);
        o[q] = v > 0.f ? v : (__expf(v) - 1.f);
    }
    const size_t oidx = (size_t)(b * N + i) * C2 + head * D + c0;
    if (final_layer) {
        *(float4*)&out_f32[oidx] = make_float4(o[0], o[1], o[2], o[3]);
        *(float4*)&out_f32[oidx + 4] = make_float4(o[4], o[5], o[6], o[7]);
    } else {
        f16x8 ov;
#pragma unroll
        for (int q = 0; q < 8; ++q) ov[q] = (f16)o[q];
        *(f16x8*)&out_f16[oidx] = ov;
    }
}

extern "C" void kernel_launch(void* const* d_in, const int* in_sizes, int n_in,
                              void* d_out, int out_size, void* d_ws, size_t ws_size,
                              hipStream_t stream)
{
    const float* x = (const float*)d_in[0];
    float* ws = (float*)d_ws;
    size_t off = 0;
    f16* xh = (f16*)(ws + off);   off += (size_t)M_ * C2 / 2;
    f16* WcT = (f16*)(ws + off);  off += (size_t)C2 * C2 / 2;
    float* h = ws + off;          off += (size_t)M_ * C2;
    float* l0 = ws + off;         off += (size_t)B_ * N;
    float* r0 = ws + off;         off += (size_t)B_ * N;
    float* l1 = ws + off;         off += (size_t)B_ * N;
    float* r1 = ws + off;         off += (size_t)B_ * N;
    float* rm1 = ws + off;        off += 16;
    float* rm2 = ws + off;        off += 16;
    int* rix = (int*)(ws + off);  off += 16;
    float* rs_s = ws + off;       off += (size_t)16 * N;
    int* perm = (int*)(ws + off); off += (size_t)16 * N;
    float* As = ws + off;         off += (size_t)16 * N;
    float* Bs = ws + off;         off += (size_t)16 * N;
    float* SAinc = ws + off;      off += (size_t)16 * N;
    float* SSBinc = ws + off;     off += (size_t)16 * N;
    f16* PA = (f16*)(ws + off);   off += (size_t)16 * N * D / 2;
    f16* PB = (f16*)(ws + off);   off += (size_t)16 * N * D / 2;
    float* totA = ws + off;       off += (size_t)16 * NCH * D;
    float* totB = ws + off;       off += (size_t)16 * NCH * D;
    float* AOff = ws + off;       off += (size_t)16 * NCH * D;
    float* BOffS = ws + off;      off += (size_t)16 * NCH * D;

    cvt_x_kernel<<<M_ * C2 / 1024, 256, 0, stream>>>(x, xh);

    for (int layer = 0; layer < 2; ++layer) {
        const int base = 2 + layer * 6;
        const float* W0 = (const float*)d_in[base + 0];
        const float* b0 = (const float*)d_in[base + 1];
        const float* a0 = (const float*)d_in[base + 2];
        const float* W1 = (const float*)d_in[base + 3];
        const float* b1 = (const float*)d_in[base + 4];
        const float* a1 = (const float*)d_in[base + 5];

        cvt_w_kernel<<<C2, C2, 0, stream>>>(W0, W1, WcT);
        gemm_mfma_kernel<<<M_ / 64, 256, 0, stream>>>(xh, WcT, b0, b1, h);
        lr_kernel<<<M_ * H / 4, 256, 0, stream>>>(h, a0, a1, l0, r0, l1, r1);
        top2_kernel<<<B_ * H, 256, 0, stream>>>(r0, r1, rm1, rm2, rix);
        sort_kernel<<<B_ * H, 256, 0, stream>>>(r0, r1, rs_s, perm, As, Bs, SAinc, SSBinc);
        scanA_kernel<<<dim3(NCH, B_ * H), 256, 0, stream>>>(h, perm, As, Bs, PA, PB, totA, totB);
        scanB_kernel<<<B_ * H, 128, 0, stream>>>(totA, totB, AOff, BOffS);
        out_kernel<<<dim3(N / 16, H, B_), 256, 0, stream>>>(
            h, l0, l1, r0, r1, rm1, rm2, rix, rs_s, SAinc, SSBinc,
            PA, PB, AOff, BOffS, (float*)d_out, xh, layer == 1 ? 1 : 0);
    }
}

// Round 4
// 235.843 us; speedup vs baseline: 5.6326x; 1.6413x over previous
//
#include <hip/hip_runtime.h>
#include <math.h>

#define ALPHA_SLOPE 0.2f

typedef _Float16 f16;
typedef f16 f16x4 __attribute__((ext_vector_type(4)));
typedef f16 f16x8 __attribute__((ext_vector_type(8)));
typedef float f32x4 __attribute__((ext_vector_type(4)));

constexpr int B_ = 8, N = 2048, F = 256, D = 128, H = 2;
constexpr int C2 = H * D;           // 256 = feature width = K of gemm
constexpr int M_ = B_ * N;          // 16384 rows
constexpr int NCH = 16;             // scan chunks
constexpr int CHL = N / NCH;        // 128 j per chunk

__device__ __forceinline__ float lrelu(float x) { return fmaxf(x, ALPHA_SLOPE * x); }

// ---------- x fp32 -> f16 ----------
__global__ __launch_bounds__(256) void cvt_x_kernel(const float* __restrict__ x, f16* __restrict__ xh)
{
    const int idx = (blockIdx.x * 256 + threadIdx.x) * 4;
    const float4 v = *(const float4*)&x[idx];
    f16x4 o; o[0] = (f16)v.x; o[1] = (f16)v.y; o[2] = (f16)v.z; o[3] = (f16)v.w;
    *(f16x4*)&xh[idx] = o;
}

// ---------- WcT[c][k] = W(head(c))[k][c%128], f16 ----------
__global__ __launch_bounds__(256) void cvt_w_kernel(const float* __restrict__ W0,
                                                    const float* __restrict__ W1,
                                                    f16* __restrict__ WcT)
{
    const int c = blockIdx.x, k = threadIdx.x;
    const float v = (c < D) ? W0[k * D + c] : W1[k * D + (c - D)];
    WcT[c * C2 + k] = (f16)v;
}

// ---------- h[M][256] = xh @ WcT^T + bias, MFMA ----------
__global__ __launch_bounds__(256) void gemm_mfma_kernel(
    const f16* __restrict__ xh, const f16* __restrict__ WcT,
    const float* __restrict__ b0, const float* __restrict__ b1,
    float* __restrict__ h)
{
    __shared__ f16 xs[64][C2 + 8];
    const int t = threadIdx.x;
    const int row0 = blockIdx.x * 64;
#pragma unroll
    for (int p = 0; p < 8; ++p) {
        const int q = p * 256 + t;
        const int row = q >> 5, cc = q & 31;
        *(f16x8*)&xs[row][cc * 8] = *(const f16x8*)&xh[(size_t)(row0 + row) * C2 + cc * 8];
    }
    __syncthreads();
    const int w = t >> 6, l = t & 63;
    const int fm = l & 15, fk = (l >> 4) * 8;
    f32x4 acc[4][4] = {};
#pragma unroll
    for (int ks = 0; ks < 8; ++ks) {
        f16x8 af[4], bf[4];
#pragma unroll
        for (int rt = 0; rt < 4; ++rt)
            af[rt] = *(const f16x8*)&xs[rt * 16 + fm][ks * 32 + fk];
#pragma unroll
        for (int ct = 0; ct < 4; ++ct) {
            const int col = w * 64 + ct * 16 + fm;
            bf[ct] = *(const f16x8*)&WcT[(size_t)col * C2 + ks * 32 + fk];
        }
#pragma unroll
        for (int rt = 0; rt < 4; ++rt)
#pragma unroll
            for (int ct = 0; ct < 4; ++ct)
                acc[rt][ct] = __builtin_amdgcn_mfma_f32_16x16x32_f16(af[rt], bf[ct], acc[rt][ct], 0, 0, 0);
    }
#pragma unroll
    for (int rt = 0; rt < 4; ++rt)
#pragma unroll
        for (int ct = 0; ct < 4; ++ct) {
            const int col = w * 64 + ct * 16 + fm;
            const float bias = (col < D) ? b0[col] : b1[col - D];
#pragma unroll
            for (int q = 0; q < 4; ++q) {
                const int row = rt * 16 + (l >> 4) * 4 + q;
                h[(size_t)(row0 + row) * C2 + col] = acc[rt][ct][q] + bias;
            }
        }
}

// ---------- l,r per (row,head) ----------
__global__ __launch_bounds__(256) void lr_kernel(
    const float* __restrict__ h,
    const float* __restrict__ a0, const float* __restrict__ a1,
    float* __restrict__ l0, float* __restrict__ r0,
    float* __restrict__ l1, float* __restrict__ r1)
{
    const int wave = threadIdx.x >> 6, lane = threadIdx.x & 63;
    const int rh = blockIdx.x * 4 + wave;
    const int row = rh >> 1, head = rh & 1;
    const float* __restrict__ hr = h + (size_t)row * C2 + head * D;
    const float* __restrict__ a = head ? a1 : a0;
    const float hv0 = hr[lane];
    const float hv1 = hr[64 + lane];
    float lv = hv0 * a[lane] + hv1 * a[64 + lane];
    float rv = hv0 * a[D + lane] + hv1 * a[D + 64 + lane];
#pragma unroll
    for (int off = 32; off; off >>= 1) {
        lv += __shfl_down(lv, off, 64);
        rv += __shfl_down(rv, off, 64);
    }
    if (lane == 0) {
        (head ? l1 : l0)[row] = lv;
        (head ? r1 : r0)[row] = rv;
    }
}

// ---------- rank sort: rank_e = #{j : r_j > r_e, ties by smaller j} ----------
// 8 blocks per bh; each thread ranks one element against all 2048 via LDS.
__global__ __launch_bounds__(256) void rank_kernel(
    const float* __restrict__ r0, const float* __restrict__ r1,
    float* __restrict__ rs_s, int* __restrict__ perm)
{
    const int bh = blockIdx.y;
    const float* __restrict__ r = ((bh & 1) ? r1 : r0) + (size_t)(bh >> 1) * N;
    __shared__ float rl[N];
    const int t = threadIdx.x;
    for (int j = t; j < N; j += 256) rl[j] = r[j];
    __syncthreads();
    const int e = blockIdx.x * 256 + t;
    const float re = rl[e];
    const int lo = blockIdx.x * 256, hi = lo + 256;
    int cnt = 0;
    // j < lo: all j < e  -> ties count
    for (int j = 0; j < lo; j += 4) {
        const float4 v = *(const float4*)&rl[j];
        cnt += (v.x >= re);
        cnt += (v.y >= re);
        cnt += (v.z >= re);
        cnt += (v.w >= re);
    }
    // mixed chunk (includes e itself; predicate is false at j==e)
    for (int j = lo; j < hi; j += 4) {
        const float4 v = *(const float4*)&rl[j];
        cnt += (v.x > re) || (v.x == re && (j + 0) < e);
        cnt += (v.y > re) || (v.y == re && (j + 1) < e);
        cnt += (v.z > re) || (v.z == re && (j + 2) < e);
        cnt += (v.w > re) || (v.w == re && (j + 3) < e);
    }
    // j >= hi: all j > e -> ties don't count
    for (int j = hi; j < N; j += 4) {
        const float4 v = *(const float4*)&rl[j];
        cnt += (v.x > re);
        cnt += (v.y > re);
        cnt += (v.z > re);
        cnt += (v.w > re);
    }
    const size_t g = (size_t)bh * N;
    rs_s[g + cnt] = re;
    perm[g + cnt] = e;
}

// ---------- weights + scalar prefix/suffix sums over sorted r ----------
__global__ __launch_bounds__(256) void scan_kernel(
    const float* __restrict__ rs_s,
    float* __restrict__ As, float* __restrict__ Bs,
    float* __restrict__ SAinc, float* __restrict__ SSBinc)
{
    const int bh = blockIdx.x;
    const size_t g = (size_t)bh * N;
    const int t = threadIdx.x;
    __shared__ float ss[256], ss2[256];
    const float c1 = rs_s[g];          // max r
    const int base = t * 8;
    float eA[8], eB[8];
    float sA = 0.f, sB = 0.f;
#pragma unroll
    for (int q = 0; q < 8; ++q) {
        const float rr = rs_s[g + base + q];
        eA[q] = __expf(rr - c1);
        eB[q] = __expf(0.2f * (rr - c1));
        sA += eA[q]; sB += eB[q];
    }
    ss[t] = sA; ss2[255 - t] = sB;
    __syncthreads();
    for (int off = 1; off < 256; off <<= 1) {
        const float v1 = (t >= off) ? ss[t - off] : 0.f;
        const float v2 = (t >= off) ? ss2[t - off] : 0.f;
        __syncthreads();
        ss[t] += v1; ss2[t] += v2;
        __syncthreads();
    }
    const float exclA = ss[t] - sA;
    const float exclB = ss2[255 - t] - sB;
    float accA = exclA;
#pragma unroll
    for (int q = 0; q < 8; ++q) {
        accA += eA[q];
        SAinc[g + base + q] = accA;
        As[g + base + q] = eA[q];
        Bs[g + base + q] = eB[q];
    }
    float accB = exclB;
#pragma unroll
    for (int q = 7; q >= 0; --q) {
        accB += eB[q];
        SSBinc[g + base + q] = accB;
    }
}

// ---------- per-chunk vector scans: PA (prefix of A*h), PB (suffix of B*h), chunk totals ----------
__global__ __launch_bounds__(256) void scanA_kernel(
    const float* __restrict__ h, const int* __restrict__ perm,
    const float* __restrict__ As, const float* __restrict__ Bs,
    f16* __restrict__ PA, f16* __restrict__ PB,
    float* __restrict__ totA, float* __restrict__ totB)
{
    const int chunk = blockIdx.x, bh = blockIdx.y;
    const int b = bh >> 1, head = bh & 1;
    __shared__ float hs[CHL][D];
    __shared__ int pj[CHL];
    __shared__ float wA[CHL], wB[CHL];
    const int t = threadIdx.x;
    const size_t g = (size_t)bh * N + chunk * CHL;
    if (t < CHL) {
        pj[t] = perm[g + t];
        wA[t] = As[g + t];
        wB[t] = Bs[g + t];
    }
    __syncthreads();
#pragma unroll
    for (int p = 0; p < 16; ++p) {
        const int q = p * 256 + t;
        const int row = q >> 5, c4 = q & 31;
        const float* src = h + (size_t)(b * N + pj[row]) * C2 + head * D;
        *(float4*)&hs[row][c4 * 4] = *(const float4*)&src[c4 * 4];
    }
    __syncthreads();
    if (t < D) {
        const int d = t;
        float acc = 0.f;
        for (int j = 0; j < CHL; ++j) {
            acc = fmaf(wA[j], hs[j][d], acc);
            PA[(g + j) * D + d] = (f16)acc;
        }
        totA[(size_t)(bh * NCH + chunk) * D + d] = acc;
    } else {
        const int d = t - D;
        float acc = 0.f;
        for (int jj = 0; jj < CHL; ++jj) {
            const int j = CHL - 1 - jj;
            acc = fmaf(wB[j], hs[j][d], acc);
            PB[(g + j) * D + d] = (f16)acc;
        }
        totB[(size_t)(bh * NCH + chunk) * D + d] = acc;
    }
}

// ---------- chunk-offset scans ----------
__global__ __launch_bounds__(128) void scanB_kernel(
    const float* __restrict__ totA, const float* __restrict__ totB,
    float* __restrict__ AOff, float* __restrict__ BOffS)
{
    const int bh = blockIdx.x, d = threadIdx.x;
    float accA = 0.f;
    for (int q = 0; q < NCH; ++q) {
        AOff[(size_t)(bh * NCH + q) * D + d] = accA;
        accA += totA[(size_t)(bh * NCH + q) * D + d];
    }
    float accB = 0.f;
    for (int q = NCH - 1; q >= 0; --q) {
        BOffS[(size_t)(bh * NCH + q) * D + d] = accB;
        accB += totB[(size_t)(bh * NCH + q) * D + d];
    }
}

// ---------- output: per row lookup + combine + elu ----------
__global__ __launch_bounds__(256) void out_kernel(
    const float* __restrict__ h,
    const float* __restrict__ l0v, const float* __restrict__ l1v,
    const float* __restrict__ r0v, const float* __restrict__ r1v,
    const int* __restrict__ perm, const float* __restrict__ rs_s,
    const float* __restrict__ SAinc, const float* __restrict__ SSBinc,
    const f16* __restrict__ PA, const f16* __restrict__ PB,
    const float* __restrict__ AOff, const float* __restrict__ BOffS,
    float* __restrict__ out_f32, f16* __restrict__ out_f16, const int final_layer)
{
    const int head = blockIdx.y, b = blockIdx.z;
    const int bh = b * H + head;
    const float* __restrict__ lv = (head ? l1v : l0v) + (size_t)b * N;
    const float* __restrict__ rv = (head ? r1v : r0v) + (size_t)b * N;
    __shared__ float rsl[N];
    const int t = threadIdx.x;
    const size_t gb = (size_t)bh * N;
    for (int j = t; j < N; j += 256) rsl[j] = rs_s[gb + j];
    __syncthreads();

    const int i = blockIdx.x * 16 + (t >> 4);
    const int c0 = (t & 15) * 8;
    const float li = lv[i];
    const float ri = rv[i];
    const float rmx1 = rsl[0];               // top-1 of r (sorted)
    const float rmx2 = rsl[1];               // top-2
    const int rdx = perm[gb];                // argmax index
    const float rmx = (i == rdx) ? rmx2 : rmx1;
    const float m = lrelu(li + rmx);
    const float c1 = rmx1;
    const float alpha = __expf(li + c1 - m);
    const float beta = __expf(0.2f * (li + c1) - m);
    const float diag = __expf(lrelu(li + ri) - m);

    int lo = 0, hi = N;
    const float thr = -li;
    while (lo < hi) {
        const int mid = (lo + hi) >> 1;
        if (rsl[mid] >= thr) lo = mid + 1; else hi = mid;
    }
    const int k = lo;

    const float SAk = (k > 0) ? SAinc[gb + k - 1] : 0.f;
    const float SBk = (k < N) ? SSBinc[gb + k] : 0.f;
    const float Z = fmaf(alpha, SAk, beta * SBk) - diag;
    const float invZ = 1.f / Z;

    float pa[8] = {}, pb[8] = {};
    if (k > 0) {
        const int kk = k - 1, ch = kk >> 7;
        const f16x8 v = *(const f16x8*)&PA[(gb + kk) * D + c0];
        const float4 o0 = *(const float4*)&AOff[(size_t)(bh * NCH + ch) * D + c0];
        const float4 o1 = *(const float4*)&AOff[(size_t)(bh * NCH + ch) * D + c0 + 4];
        pa[0] = (float)v[0] + o0.x; pa[1] = (float)v[1] + o0.y;
        pa[2] = (float)v[2] + o0.z; pa[3] = (float)v[3] + o0.w;
        pa[4] = (float)v[4] + o1.x; pa[5] = (float)v[5] + o1.y;
        pa[6] = (float)v[6] + o1.z; pa[7] = (float)v[7] + o1.w;
    }
    if (k < N) {
        const int ch = k >> 7;
        const f16x8 v = *(const f16x8*)&PB[(gb + k) * D + c0];
        const float4 o0 = *(const float4*)&BOffS[(size_t)(bh * NCH + ch) * D + c0];
        const float4 o1 = *(const float4*)&BOffS[(size_t)(bh * NCH + ch) * D + c0 + 4];
        pb[0] = (float)v[0] + o0.x; pb[1] = (float)v[1] + o0.y;
        pb[2] = (float)v[2] + o0.z; pb[3] = (float)v[3] + o0.w;
        pb[4] = (float)v[4] + o1.x; pb[5] = (float)v[5] + o1.y;
        pb[6] = (float)v[6] + o1.z; pb[7] = (float)v[7] + o1.w;
    }

    const float* hr = h + (size_t)(b * N + i) * C2 + head * D + c0;
    const float4 h0v = *(const float4*)&hr[0];
    const float4 h1v = *(const float4*)&hr[4];
    const float hv[8] = {h0v.x, h0v.y, h0v.z, h0v.w, h1v.x, h1v.y, h1v.z, h1v.w};
    float o[8];
#pragma unroll
    for (int q = 0; q < 8; ++q) {
        const float num = alpha * pa[q] + beta * pb[q] - diag * hv[q];
        float v = fmaf(num, invZ, hv[q]);
        o[q] = v > 0.f ? v : (__expf(v) - 1.f);
    }
    const size_t oidx = (size_t)(b * N + i) * C2 + head * D + c0;
    if (final_layer) {
        *(float4*)&out_f32[oidx] = make_float4(o[0], o[1], o[2], o[3]);
        *(float4*)&out_f32[oidx + 4] = make_float4(o[4], o[5], o[6], o[7]);
    } else {
        f16x8 ov;
#pragma unroll
        for (int q = 0; q < 8; ++q) ov[q] = (f16)o[q];
        *(f16x8*)&out_f16[oidx] = ov;
    }
}

extern "C" void kernel_launch(void* const* d_in, const int* in_sizes, int n_in,
                              void* d_out, int out_size, void* d_ws, size_t ws_size,
                              hipStream_t stream)
{
    const float* x = (const float*)d_in[0];
    float* ws = (float*)d_ws;
    size_t off = 0;
    f16* xh = (f16*)(ws + off);   off += (size_t)M_ * C2 / 2;
    f16* WcT = (f16*)(ws + off);  off += (size_t)C2 * C2 / 2;
    float* h = ws + off;          off += (size_t)M_ * C2;
    float* l0 = ws + off;         off += (size_t)B_ * N;
    float* r0 = ws + off;         off += (size_t)B_ * N;
    float* l1 = ws + off;         off += (size_t)B_ * N;
    float* r1 = ws + off;         off += (size_t)B_ * N;
    float* rs_s = ws + off;       off += (size_t)16 * N;
    int* perm = (int*)(ws + off); off += (size_t)16 * N;
    float* As = ws + off;         off += (size_t)16 * N;
    float* Bs = ws + off;         off += (size_t)16 * N;
    float* SAinc = ws + off;      off += (size_t)16 * N;
    float* SSBinc = ws + off;     off += (size_t)16 * N;
    f16* PA = (f16*)(ws + off);   off += (size_t)16 * N * D / 2;
    f16* PB = (f16*)(ws + off);   off += (size_t)16 * N * D / 2;
    float* totA = ws + off;       off += (size_t)16 * NCH * D;
    float* totB = ws + off;       off += (size_t)16 * NCH * D;
    float* AOff = ws + off;       off += (size_t)16 * NCH * D;
    float* BOffS = ws + off;      off += (size_t)16 * NCH * D;

    cvt_x_kernel<<<M_ * C2 / 1024, 256, 0, stream>>>(x, xh);

    for (int layer = 0; layer < 2; ++layer) {
        const int base = 2 + layer * 6;
        const float* W0 = (const float*)d_in[base + 0];
        const float* b0 = (const float*)d_in[base + 1];
        const float* a0 = (const float*)d_in[base + 2];
        const float* W1 = (const float*)d_in[base + 3];
        const float* b1 = (const float*)d_in[base + 4];
        const float* a1 = (const float*)d_in[base + 5];

        cvt_w_kernel<<<C2, C2, 0, stream>>>(W0, W1, WcT);
        gemm_mfma_kernel<<<M_ / 64, 256, 0, stream>>>(xh, WcT, b0, b1, h);
        lr_kernel<<<M_ * H / 4, 256, 0, stream>>>(h, a0, a1, l0, r0, l1, r1);
        rank_kernel<<<dim3(N / 256, B_ * H), 256, 0, stream>>>(r0, r1, rs_s, perm);
        scan_kernel<<<B_ * H, 256, 0, stream>>>(rs_s, As, Bs, SAinc, SSBinc);
        scanA_kernel<<<dim3(NCH, B_ * H), 256, 0, stream>>>(h, perm, As, Bs, PA, PB, totA, totB);
        scanB_kernel<<<B_ * H, 128, 0, stream>>>(totA, totB, AOff, BOffS);
        out_kernel<<<dim3(N / 16, H, B_), 256, 0, stream>>>(
            h, l0, l1, r0, r1, perm, rs_s, SAinc, SSBinc,
            PA, PB, AOff, BOffS, (float*)d_out, xh, layer == 1 ? 1 : 0);
    }
}

// Round 5
// 233.048 us; speedup vs baseline: 5.7001x; 1.0120x over previous
//
#include <hip/hip_runtime.h>
#include <math.h>

#define ALPHA_SLOPE 0.2f

typedef _Float16 f16;
typedef f16 f16x4 __attribute__((ext_vector_type(4)));
typedef f16 f16x8 __attribute__((ext_vector_type(8)));
typedef float f32x4 __attribute__((ext_vector_type(4)));

constexpr int B_ = 8, N = 2048, F = 256, D = 128, H = 2;
constexpr int C2 = H * D;           // 256
constexpr int M_ = B_ * N;          // 16384
constexpr int NCH = 16;             // scan chunks
constexpr int CHL = N / NCH;        // 128

__device__ __forceinline__ float lrelu(float x) { return fmaxf(x, ALPHA_SLOPE * x); }

// ---------- x fp32 -> f16 ----------
__global__ __launch_bounds__(256) void cvt_x_kernel(const float* __restrict__ x, f16* __restrict__ xh)
{
    const int idx = (blockIdx.x * 256 + threadIdx.x) * 4;
    const float4 v = *(const float4*)&x[idx];
    f16x4 o; o[0] = (f16)v.x; o[1] = (f16)v.y; o[2] = (f16)v.z; o[3] = (f16)v.w;
    *(f16x4*)&xh[idx] = o;
}

// ---------- both layers' W -> WcT[layer][c][k] f16 ----------
__global__ __launch_bounds__(256) void cvt_w_kernel(
    const float* __restrict__ W00, const float* __restrict__ W01,
    const float* __restrict__ W10, const float* __restrict__ W11,
    f16* __restrict__ WcT)
{
    const int c = blockIdx.x, k = threadIdx.x, layer = blockIdx.y;
    const float* __restrict__ W0 = layer ? W10 : W00;
    const float* __restrict__ W1 = layer ? W11 : W01;
    const float v = (c < D) ? W0[k * D + c] : W1[k * D + (c - D)];
    WcT[(size_t)layer * C2 * C2 + c * C2 + k] = (f16)v;
}

// ---------- fused: h = xh@WcT^T + bias (MFMA), coalesced h store, l/r from LDS tile ----------
__global__ __launch_bounds__(256) void gemm_lr_kernel(
    const f16* __restrict__ xh, const f16* __restrict__ WcT,
    const float* __restrict__ b0, const float* __restrict__ b1,
    const float* __restrict__ a0, const float* __restrict__ a1,
    float* __restrict__ h,
    float* __restrict__ l0, float* __restrict__ r0,
    float* __restrict__ l1, float* __restrict__ r1)
{
    __shared__ float hts[64][C2 + 4];                   // 66560 B; row stride 1040 B (16B aligned)
    f16 (*xs)[C2 + 8] = (f16 (*)[C2 + 8])hts;           // alias: x staging (33792 B) used first

    const int t = threadIdx.x;
    const int row0 = blockIdx.x * 64;
#pragma unroll
    for (int p = 0; p < 8; ++p) {
        const int q = p * 256 + t;
        const int row = q >> 5, cc = q & 31;
        *(f16x8*)&xs[row][cc * 8] = *(const f16x8*)&xh[(size_t)(row0 + row) * C2 + cc * 8];
    }
    __syncthreads();
    const int w = t >> 6, l = t & 63;
    const int fm = l & 15, fk = (l >> 4) * 8;
    f32x4 acc[4][4] = {};
#pragma unroll
    for (int ks = 0; ks < 8; ++ks) {
        f16x8 af[4], bf[4];
#pragma unroll
        for (int rt = 0; rt < 4; ++rt)
            af[rt] = *(const f16x8*)&xs[rt * 16 + fm][ks * 32 + fk];
#pragma unroll
        for (int ct = 0; ct < 4; ++ct) {
            const int col = w * 64 + ct * 16 + fm;
            bf[ct] = *(const f16x8*)&WcT[(size_t)col * C2 + ks * 32 + fk];
        }
#pragma unroll
        for (int rt = 0; rt < 4; ++rt)
#pragma unroll
            for (int ct = 0; ct < 4; ++ct)
                acc[rt][ct] = __builtin_amdgcn_mfma_f32_16x16x32_f16(af[rt], bf[ct], acc[rt][ct], 0, 0, 0);
    }
    __syncthreads();   // xs reads done; reuse LDS as h-tile
    // acc -> LDS tile (+bias)
#pragma unroll
    for (int rt = 0; rt < 4; ++rt)
#pragma unroll
        for (int ct = 0; ct < 4; ++ct) {
            const int col = w * 64 + ct * 16 + fm;
            const float bias = (col < D) ? b0[col] : b1[col - D];
#pragma unroll
            for (int q = 0; q < 4; ++q) {
                const int row = rt * 16 + (l >> 4) * 4 + q;
                hts[row][col] = acc[rt][ct][q] + bias;
            }
        }
    __syncthreads();
    // coalesced h store: 4096 float4
#pragma unroll
    for (int p = 0; p < 16; ++p) {
        const int q = p * 256 + t;
        const int row = q >> 6, c4 = q & 63;
        *(float4*)&h[(size_t)(row0 + row) * C2 + c4 * 4] = *(const float4*)&hts[row][c4 * 4];
    }
    // l/r: lane handles (row = w*16 + (l&15), quarter = l>>4 -> 64 cols)
    const int lrow = w * 16 + (l & 15);
    const int qtr = l >> 4;
    const float* __restrict__ ab = (qtr >= 2) ? a1 : a0;
    const int cb = (qtr & 1) * 64;
    float lv = 0.f, rv = 0.f;
#pragma unroll
    for (int c4 = 0; c4 < 16; ++c4) {
        const float4 hv = *(const float4*)&hts[lrow][qtr * 64 + c4 * 4];
        const float4 alv = *(const float4*)&ab[cb + c4 * 4];
        const float4 arv = *(const float4*)&ab[128 + cb + c4 * 4];
        lv += hv.x * alv.x + hv.y * alv.y + hv.z * alv.z + hv.w * alv.w;
        rv += hv.x * arv.x + hv.y * arv.y + hv.z * arv.z + hv.w * arv.w;
    }
    lv += __shfl_xor(lv, 16, 64);   // combine quarter pairs (0,1) and (2,3)
    rv += __shfl_xor(rv, 16, 64);
    const int grow = row0 + lrow;
    if (qtr == 0) { l0[grow] = lv; r0[grow] = rv; }
    else if (qtr == 2) { l1[grow] = lv; r1[grow] = rv; }
}

// ---------- rank sort + k_i count ----------
__global__ __launch_bounds__(256) void rank_kernel(
    const float* __restrict__ r0, const float* __restrict__ r1,
    const float* __restrict__ l0, const float* __restrict__ l1,
    float* __restrict__ rs_s, int* __restrict__ perm, int* __restrict__ kout)
{
    const int bh = blockIdx.y;
    const float* __restrict__ r = ((bh & 1) ? r1 : r0) + (size_t)(bh >> 1) * N;
    const float* __restrict__ lp = ((bh & 1) ? l1 : l0) + (size_t)(bh >> 1) * N;
    __shared__ float rl[N];
    const int t = threadIdx.x;
    for (int j = t; j < N; j += 256) rl[j] = r[j];
    __syncthreads();
    const int e = blockIdx.x * 256 + t;
    const float re = rl[e];
    const float thr = -lp[e];
    const int lo = blockIdx.x * 256, hi = lo + 256;
    int cnt = 0, k2 = 0;
    for (int j = 0; j < lo; j += 4) {
        const float4 v = *(const float4*)&rl[j];
        cnt += (v.x >= re) + (v.y >= re) + (v.z >= re) + (v.w >= re);
        k2  += (v.x >= thr) + (v.y >= thr) + (v.z >= thr) + (v.w >= thr);
    }
    for (int j = lo; j < hi; j += 4) {
        const float4 v = *(const float4*)&rl[j];
        cnt += (v.x > re) || (v.x == re && (j + 0) < e);
        cnt += (v.y > re) || (v.y == re && (j + 1) < e);
        cnt += (v.z > re) || (v.z == re && (j + 2) < e);
        cnt += (v.w > re) || (v.w == re && (j + 3) < e);
        k2  += (v.x >= thr) + (v.y >= thr) + (v.z >= thr) + (v.w >= thr);
    }
    for (int j = hi; j < N; j += 4) {
        const float4 v = *(const float4*)&rl[j];
        cnt += (v.x > re) + (v.y > re) + (v.z > re) + (v.w > re);
        k2  += (v.x >= thr) + (v.y >= thr) + (v.z >= thr) + (v.w >= thr);
    }
    const size_t g = (size_t)bh * N;
    rs_s[g + cnt] = re;
    perm[g + cnt] = e;
    kout[g + e] = k2;
}

// ---------- fused chunk scans: weights from rs_s, scalar local scans, vector scans, totals ----------
__global__ __launch_bounds__(256) void scanA_kernel(
    const float* __restrict__ h, const int* __restrict__ perm,
    const float* __restrict__ rs_s,
    f16* __restrict__ PA, f16* __restrict__ PB,
    float* __restrict__ SAloc, float* __restrict__ SBloc,
    float* __restrict__ totA, float* __restrict__ totB,
    float* __restrict__ stA, float* __restrict__ stB)
{
    const int chunk = blockIdx.x, bh = blockIdx.y;
    const int b = bh >> 1, head = bh & 1;
    __shared__ float hs[CHL][D];
    __shared__ int pj[CHL];
    __shared__ float wA[CHL], wB[CHL];
    __shared__ float buf[256];
    const int t = threadIdx.x;
    const size_t g = (size_t)bh * N + chunk * CHL;
    const float c1 = rs_s[(size_t)bh * N];
    if (t < CHL) {
        pj[t] = perm[g + t];
        const float rr = rs_s[g + t];
        const float eA = __expf(rr - c1);
        const float eB = __expf(0.2f * (rr - c1));
        wA[t] = eA; wB[t] = eB;
        buf[t] = eA;
    } else {
        const float rr = rs_s[g + (127 - (t - 128))];
        buf[t] = __expf(0.2f * (rr - c1));   // reversed B for suffix via prefix
    }
    __syncthreads();
    // Hillis-Steele prefix within each 128-half
    const int li = t & 127;
#pragma unroll
    for (int off = 1; off < 128; off <<= 1) {
        const float v = (li >= off) ? buf[t - off] : 0.f;
        __syncthreads();
        buf[t] += v;
        __syncthreads();
    }
    if (t < 128) SAloc[g + t] = buf[t];
    else SBloc[g + (127 - li)] = buf[t];
    if (t == 127) stA[bh * NCH + chunk] = buf[127];
    if (t == 255) stB[bh * NCH + chunk] = buf[255];
    // gather h rows (permuted)
#pragma unroll
    for (int p = 0; p < 16; ++p) {
        const int q = p * 256 + t;
        const int row = q >> 5, c4 = q & 31;
        const float* src = h + (size_t)(b * N + pj[row]) * C2 + head * D;
        *(float4*)&hs[row][c4 * 4] = *(const float4*)&src[c4 * 4];
    }
    __syncthreads();
    if (t < D) {
        const int d = t;
        float acc = 0.f;
        for (int j = 0; j < CHL; ++j) {
            acc = fmaf(wA[j], hs[j][d], acc);
            PA[(g + j) * D + d] = (f16)acc;
        }
        totA[(size_t)(bh * NCH + chunk) * D + d] = acc;
    } else {
        const int d = t - D;
        float acc = 0.f;
        for (int jj = 0; jj < CHL; ++jj) {
            const int j = CHL - 1 - jj;
            acc = fmaf(wB[j], hs[j][d], acc);
            PB[(g + j) * D + d] = (f16)acc;
        }
        totB[(size_t)(bh * NCH + chunk) * D + d] = acc;
    }
}

// ---------- chunk offsets: vector (AOff/BOffS) + scalar (sAOff/sBOff) ----------
__global__ __launch_bounds__(128) void scanB_kernel(
    const float* __restrict__ totA, const float* __restrict__ totB,
    const float* __restrict__ stA, const float* __restrict__ stB,
    float* __restrict__ AOff, float* __restrict__ BOffS,
    float* __restrict__ sAOff, float* __restrict__ sBOff)
{
    const int bh = blockIdx.x, d = threadIdx.x;
    float accA = 0.f;
    for (int q = 0; q < NCH; ++q) {
        AOff[(size_t)(bh * NCH + q) * D + d] = accA;
        accA += totA[(size_t)(bh * NCH + q) * D + d];
    }
    float accB = 0.f;
    for (int q = NCH - 1; q >= 0; --q) {
        BOffS[(size_t)(bh * NCH + q) * D + d] = accB;
        accB += totB[(size_t)(bh * NCH + q) * D + d];
    }
    if (d == 0) {
        float a = 0.f;
        for (int q = 0; q < NCH; ++q) { sAOff[bh * NCH + q] = a; a += stA[bh * NCH + q]; }
    } else if (d == 1) {
        float a = 0.f;
        for (int q = NCH - 1; q >= 0; --q) { sBOff[bh * NCH + q] = a; a += stB[bh * NCH + q]; }
    }
}

// ---------- output: pure streaming combine + elu (no LDS, no search) ----------
__global__ __launch_bounds__(256) void out_kernel(
    const float* __restrict__ h,
    const float* __restrict__ l0v, const float* __restrict__ l1v,
    const float* __restrict__ r0v, const float* __restrict__ r1v,
    const int* __restrict__ perm, const float* __restrict__ rs_s,
    const int* __restrict__ kout,
    const float* __restrict__ SAloc, const float* __restrict__ SBloc,
    const float* __restrict__ sAOff, const float* __restrict__ sBOff,
    const f16* __restrict__ PA, const f16* __restrict__ PB,
    const float* __restrict__ AOff, const float* __restrict__ BOffS,
    float* __restrict__ out_f32, f16* __restrict__ out_f16, const int final_layer)
{
    const int head = blockIdx.y, b = blockIdx.z;
    const int bh = b * H + head;
    const float* __restrict__ lv = (head ? l1v : l0v) + (size_t)b * N;
    const float* __restrict__ rv = (head ? r1v : r0v) + (size_t)b * N;
    const int t = threadIdx.x;
    const size_t gb = (size_t)bh * N;

    const int i = blockIdx.x * 16 + (t >> 4);
    const int c0 = (t & 15) * 8;
    const float li = lv[i];
    const float ri = rv[i];
    const float rmx1 = rs_s[gb];
    const float rmx2 = rs_s[gb + 1];
    const int rdx = perm[gb];
    const float rmx = (i == rdx) ? rmx2 : rmx1;
    const float m = lrelu(li + rmx);
    const float c1 = rmx1;
    const float alpha = __expf(li + c1 - m);
    const float beta = __expf(0.2f * (li + c1) - m);
    const float diag = __expf(lrelu(li + ri) - m);

    const int k = kout[gb + i];

    const float SAk = (k > 0) ? (sAOff[bh * NCH + ((k - 1) >> 7)] + SAloc[gb + k - 1]) : 0.f;
    const float SBk = (k < N) ? (sBOff[bh * NCH + (k >> 7)] + SBloc[gb + k]) : 0.f;
    const float Z = fmaf(alpha, SAk, beta * SBk) - diag;
    const float invZ = 1.f / Z;

    float pa[8] = {}, pb[8] = {};
    if (k > 0) {
        const int kk = k - 1, ch = kk >> 7;
        const f16x8 v = *(const f16x8*)&PA[(gb + kk) * D + c0];
        const float4 o0 = *(const float4*)&AOff[(size_t)(bh * NCH + ch) * D + c0];
        const float4 o1 = *(const float4*)&AOff[(size_t)(bh * NCH + ch) * D + c0 + 4];
        pa[0] = (float)v[0] + o0.x; pa[1] = (float)v[1] + o0.y;
        pa[2] = (float)v[2] + o0.z; pa[3] = (float)v[3] + o0.w;
        pa[4] = (float)v[4] + o1.x; pa[5] = (float)v[5] + o1.y;
        pa[6] = (float)v[6] + o1.z; pa[7] = (float)v[7] + o1.w;
    }
    if (k < N) {
        const int ch = k >> 7;
        const f16x8 v = *(const f16x8*)&PB[(gb + k) * D + c0];
        const float4 o0 = *(const float4*)&BOffS[(size_t)(bh * NCH + ch) * D + c0];
        const float4 o1 = *(const float4*)&BOffS[(size_t)(bh * NCH + ch) * D + c0 + 4];
        pb[0] = (float)v[0] + o0.x; pb[1] = (float)v[1] + o0.y;
        pb[2] = (float)v[2] + o0.z; pb[3] = (float)v[3] + o0.w;
        pb[4] = (float)v[4] + o1.x; pb[5] = (float)v[5] + o1.y;
        pb[6] = (float)v[6] + o1.z; pb[7] = (float)v[7] + o1.w;
    }

    const float* hr = h + (size_t)(b * N + i) * C2 + head * D + c0;
    const float4 h0v = *(const float4*)&hr[0];
    const float4 h1v = *(const float4*)&hr[4];
    const float hv[8] = {h0v.x, h0v.y, h0v.z, h0v.w, h1v.x, h1v.y, h1v.z, h1v.w};
    float o[8];
#pragma unroll
    for (int q = 0; q < 8; ++q) {
        const float num = alpha * pa[q] + beta * pb[q] - diag * hv[q];
        float v = fmaf(num, invZ, hv[q]);
        o[q] = v > 0.f ? v : (__expf(v) - 1.f);
    }
    const size_t oidx = (size_t)(b * N + i) * C2 + head * D + c0;
    if (final_layer) {
        *(float4*)&out_f32[oidx] = make_float4(o[0], o[1], o[2], o[3]);
        *(float4*)&out_f32[oidx + 4] = make_float4(o[4], o[5], o[6], o[7]);
    } else {
        f16x8 ov;
#pragma unroll
        for (int q = 0; q < 8; ++q) ov[q] = (f16)o[q];
        *(f16x8*)&out_f16[oidx] = ov;
    }
}

extern "C" void kernel_launch(void* const* d_in, const int* in_sizes, int n_in,
                              void* d_out, int out_size, void* d_ws, size_t ws_size,
                              hipStream_t stream)
{
    const float* x = (const float*)d_in[0];
    float* ws = (float*)d_ws;
    size_t off = 0;
    f16* xh = (f16*)(ws + off);   off += (size_t)M_ * C2 / 2;
    f16* WcT = (f16*)(ws + off);  off += (size_t)C2 * C2;        // f16, 2 layers
    float* h = ws + off;          off += (size_t)M_ * C2;
    float* l0 = ws + off;         off += (size_t)B_ * N;
    float* r0 = ws + off;         off += (size_t)B_ * N;
    float* l1 = ws + off;         off += (size_t)B_ * N;
    float* r1 = ws + off;         off += (size_t)B_ * N;
    float* rs_s = ws + off;       off += (size_t)16 * N;
    int* perm = (int*)(ws + off); off += (size_t)16 * N;
    int* kout = (int*)(ws + off); off += (size_t)16 * N;
    float* SAloc = ws + off;      off += (size_t)16 * N;
    float* SBloc = ws + off;      off += (size_t)16 * N;
    f16* PA = (f16*)(ws + off);   off += (size_t)16 * N * D / 2;
    f16* PB = (f16*)(ws + off);   off += (size_t)16 * N * D / 2;
    float* totA = ws + off;       off += (size_t)16 * NCH * D;
    float* totB = ws + off;       off += (size_t)16 * NCH * D;
    float* AOff = ws + off;       off += (size_t)16 * NCH * D;
    float* BOffS = ws + off;      off += (size_t)16 * NCH * D;
    float* stA = ws + off;        off += (size_t)16 * NCH;
    float* stB = ws + off;        off += (size_t)16 * NCH;
    float* sAOff = ws + off;      off += (size_t)16 * NCH;
    float* sBOff = ws + off;      off += (size_t)16 * NCH;

    cvt_x_kernel<<<M_ * C2 / 1024, 256, 0, stream>>>(x, xh);
    cvt_w_kernel<<<dim3(C2, 2), C2, 0, stream>>>(
        (const float*)d_in[2], (const float*)d_in[5],
        (const float*)d_in[8], (const float*)d_in[11], WcT);

    for (int layer = 0; layer < 2; ++layer) {
        const int base = 2 + layer * 6;
        const float* b0 = (const float*)d_in[base + 1];
        const float* a0 = (const float*)d_in[base + 2];
        const float* b1 = (const float*)d_in[base + 4];
        const float* a1 = (const float*)d_in[base + 5];

        gemm_lr_kernel<<<M_ / 64, 256, 0, stream>>>(
            xh, WcT + (size_t)layer * C2 * C2, b0, b1, a0, a1, h, l0, r0, l1, r1);
        rank_kernel<<<dim3(N / 256, B_ * H), 256, 0, stream>>>(r0, r1, l0, l1, rs_s, perm, kout);
        scanA_kernel<<<dim3(NCH, B_ * H), 256, 0, stream>>>(
            h, perm, rs_s, PA, PB, SAloc, SBloc, totA, totB, stA, stB);
        scanB_kernel<<<B_ * H, 128, 0, stream>>>(totA, totB, stA, stB, AOff, BOffS, sAOff, sBOff);
        out_kernel<<<dim3(N / 16, H, B_), 256, 0, stream>>>(
            h, l0, l1, r0, r1, perm, rs_s, kout, SAloc, SBloc, sAOff, sBOff,
            PA, PB, AOff, BOffS, (float*)d_out, xh, layer == 1 ? 1 : 0);
    }
}